// Round 8
// baseline (213.086 us; speedup 1.0000x reference)
//
#include <hip/hip_runtime.h>
#include <hip/hip_bf16.h>
#include <cstdint>

// B=8, S=1024, D=768, H=12, DH=64. PATCHES/2 = 512.
// Pipeline (4 dispatches):
//  k_prep    : X fp32 -> bf16  AND  Wq/Wk/Wv/Wo fp32 [K][N] -> bf16 [N][K] (stacked)
//  k_gemm_qkv: X@W{q,k,v}+b (BK=32 dbuf; 2 waves/block, wave-tile 64x128 to cut
//              LDS-read bytes/FLOP -- kernel is LDS-BW-bound)
//              -> Qw[bh][512][64] (pre-scaled log2e/8), Kw[bh][1024][64], Vt[bh][64][1024]
//  k_attn    : rows<512: ctx = softmax(QK^T)V -> Ctx bf16 [4096][768]; qt==0 blocks
//              also accumulate mv[b][768] = mean_s V
//  k_gemm_o  : out rows s<512 = Ctx@Wo + bo (double-buffered); blocks >=192 do the
//              tail (orow[b]=mv[b]@Wo+bo broadcast into out rows s>=512)

typedef __bf16 bf16_t;
typedef bf16_t bf16x8 __attribute__((ext_vector_type(8)));
typedef float f32x4 __attribute__((ext_vector_type(4)));

#define QSCALE 0.18033688011112042f  // log2(e)/8

__device__ __forceinline__ f32x4 mfma16(bf16x8 a, bf16x8 b, f32x4 c) {
  return __builtin_amdgcn_mfma_f32_16x16x32_bf16(a, b, c, 0, 0, 0);
}
__device__ __forceinline__ unsigned packbf(float x, float y) {
  union { bf16_t h; unsigned short u; } a, b;
  a.h = (bf16_t)x; b.h = (bf16_t)y;
  return (unsigned)a.u | ((unsigned)b.u << 16);
}
__device__ __forceinline__ unsigned short tobf(float x) {
  union { bf16_t h; unsigned short u; } a; a.h = (bf16_t)x; return a.u;
}
__device__ __forceinline__ void glds16(const void* g, void* s) {
  __builtin_amdgcn_global_load_lds((const __attribute__((address_space(1))) void*)g,
                                   (__attribute__((address_space(3))) void*)s, 16, 0, 0);
}

// ---------------- prep: X->bf16 (blocks 0..3071) + W transpose (blocks 3072..3647) ----
__global__ __launch_bounds__(256) void k_prep(const float* __restrict__ X,
                                              const float* __restrict__ Wq,
                                              const float* __restrict__ Wk,
                                              const float* __restrict__ Wv,
                                              const float* __restrict__ Wo,
                                              unsigned short* __restrict__ Xbf,
                                              unsigned short* __restrict__ Wt) {
  __shared__ float tile[64][65];
  if (blockIdx.x < 3072) {
    int i = blockIdx.x * 256 + threadIdx.x;  // 786432 groups of 8 floats
    const float4* p = (const float4*)X;
    float4 a = p[2 * i], b = p[2 * i + 1];
    uint4 o;
    o.x = packbf(a.x, a.y); o.y = packbf(a.z, a.w);
    o.z = packbf(b.x, b.y); o.w = packbf(b.z, b.w);
    ((uint4*)Xbf)[i] = o;
    return;
  }
  int id = blockIdx.x - 3072;       // 576 transpose blocks
  int which = id / 144;
  int rem = id - which * 144;
  const float* W = (which == 0) ? Wq : (which == 1) ? Wk : (which == 2) ? Wv : Wo;
  int k0 = (rem / 12) * 64, n0 = (rem % 12) * 64;
  int t = threadIdx.x;
  int c = t & 63, r0 = t >> 6;
#pragma unroll
  for (int i = 0; i < 16; ++i) {
    int r = r0 + i * 4;
    tile[r][c] = W[(size_t)(k0 + r) * 768 + n0 + c];
  }
  __syncthreads();
#pragma unroll
  for (int i = 0; i < 16; ++i) {
    int nr = r0 + i * 4;
    Wt[(size_t)(which * 768 + n0 + nr) * 768 + k0 + c] = tobf(tile[c][nr]);
  }
}

// ---------------- QKV GEMM: M=8192 (Q tiles skipped for s>=512), N=2304, K=768 ----------
// 128-thread blocks, 2 waves, wave-tile 64x128 (acc 4x8): LDS bytes per block-step
// = 16KB write + 24KB read (vs 48KB total for the 4-wave 64x64 layout). BK=32
// double-buffered, prefetch-before-compute, one barrier per half-step.
__global__ __launch_bounds__(128) void k_gemm_qkv(
    const unsigned short* __restrict__ Xbf, const unsigned short* __restrict__ Wt,
    const float* __restrict__ bq, const float* __restrict__ bk, const float* __restrict__ bv,
    unsigned short* __restrict__ Qw, unsigned short* __restrict__ Kw,
    unsigned short* __restrict__ Vt) {
  __shared__ __align__(16) unsigned short As0[4096], Bs0[4096], As1[4096], Bs1[4096];
  int id = blockIdx.x;
  int mt, nt;
  if (id < 576) { int mf = id / 18; mt = ((mf >> 2) << 3) + (mf & 3); nt = id - mf * 18; }
  else { int j = id - 576; int mh = j / 12; mt = ((mh >> 2) << 3) + 4 + (mh & 3); nt = 6 + (j - mh * 12); }
  const int m0 = mt * 128, n0 = nt * 128;
  const int tid = threadIdx.x, w = tid >> 6, l = tid & 63, lr = l & 15, lg = l >> 4;
  // staging: wave w stages rows w*64..w*64+63 of both A and B in 4 chunks of 16 rows.
  // lane l: row = chunk*16 + (l>>2), col = (l&3)*8. LDS [128][32] row-major.
  const unsigned short* gA = Xbf + (size_t)(m0 + w * 64 + (l >> 2)) * 768 + (l & 3) * 8;
  const unsigned short* gB = Wt + (size_t)(n0 + w * 64 + (l >> 2)) * 768 + (l & 3) * 8;
  const int woff = w * 2048;
  // fragment reads: af[i] = own-wave A rows; bf[j] = all 128 B cols
  const int rAo = woff + lr * 32 + lg * 8;
  const int rBo = lr * 32 + lg * 8;
  f32x4 acc[4][8] = {};

#define QKV_STAGE(bufA, bufB, ko)                                              \
  {                                                                            \
    glds16(gA + (ko), bufA + woff);                                            \
    glds16(gA + 16 * 768 + (ko), bufA + woff + 512);                           \
    glds16(gA + 32 * 768 + (ko), bufA + woff + 1024);                          \
    glds16(gA + 48 * 768 + (ko), bufA + woff + 1536);                          \
    glds16(gB + (ko), bufB + woff);                                            \
    glds16(gB + 16 * 768 + (ko), bufB + woff + 512);                           \
    glds16(gB + 32 * 768 + (ko), bufB + woff + 1024);                          \
    glds16(gB + 48 * 768 + (ko), bufB + woff + 1536);                          \
  }
#define QKV_COMPUTE(bufA, bufB)                                                \
  {                                                                            \
    bf16x8 af[4], bfr[8];                                                      \
    _Pragma("unroll") for (int i = 0; i < 4; ++i)                              \
      af[i] = *(const bf16x8*)(bufA + rAo + i * 512);                          \
    _Pragma("unroll") for (int j = 0; j < 8; ++j)                              \
      bfr[j] = *(const bf16x8*)(bufB + rBo + j * 512);                         \
    _Pragma("unroll") for (int i = 0; i < 4; ++i)                              \
      _Pragma("unroll") for (int j = 0; j < 8; ++j)                            \
        acc[i][j] = mfma16(af[i], bfr[j], acc[i][j]);                          \
  }

  QKV_STAGE(As0, Bs0, 0);
  __syncthreads();
  for (int kk = 0; kk < 12; ++kk) {
    const int ko = kk * 64;
    QKV_STAGE(As1, Bs1, ko + 32);
    QKV_COMPUTE(As0, Bs0);
    __syncthreads();
    if (kk < 11) { QKV_STAGE(As0, Bs0, ko + 64); }
    QKV_COMPUTE(As1, Bs1);
    __syncthreads();
  }
#undef QKV_STAGE
#undef QKV_COMPUTE

  // epilogue: C row = m0 + w*64 + mf*16 + lg*4 + rg ; col = n0 + nf*16 + lr
  const int rbase = m0 + w * 64 + lg * 4;
  const int cbase = n0 + lr;
#pragma unroll
  for (int nf = 0; nf < 8; ++nf) {
    const int n = cbase + nf * 16;
#pragma unroll
    for (int mf = 0; mf < 4; ++mf) {
      const int r = rbase + mf * 16;
      const int b = r >> 10, s = r & 1023;
      if (n < 768) {  // Q (only s<512 tiles reach here by construction)
        const int h = n >> 6, dh = n & 63;
        const float bias = bq[n];
        unsigned short* qp = Qw + ((size_t)(b * 12 + h) * 512 + s) * 64 + dh;
#pragma unroll
        for (int rg = 0; rg < 4; ++rg)
          qp[(size_t)rg * 64] = tobf((acc[mf][nf][rg] + bias) * QSCALE);
      } else if (n < 1536) {  // K
        const int d = n - 768, h = d >> 6, dh = d & 63;
        const float bias = bk[d];
        unsigned short* kp = Kw + ((size_t)(b * 12 + h) * 1024 + s) * 64 + dh;
#pragma unroll
        for (int rg = 0; rg < 4; ++rg)
          kp[(size_t)rg * 64] = tobf(acc[mf][nf][rg] + bias);
      } else {  // V -> transposed Vt[bh][dh][s], 4 consecutive s packed as 8B
        const int d = n - 1536, h = d >> 6, dh = d & 63;
        const float bias = bv[d];
        uint2 pv;
        pv.x = packbf(acc[mf][nf][0] + bias, acc[mf][nf][1] + bias);
        pv.y = packbf(acc[mf][nf][2] + bias, acc[mf][nf][3] + bias);
        *(uint2*)(Vt + ((size_t)(b * 12 + h) * 64 + dh) * 1024 + s) = pv;
      }
    }
  }
}

// ---------------- attention for q rows < 512 (+ mean-of-V for qt==0 blocks) ----------
// 1D grid 768: bh = id%96 (all 8 q-tiles of a bh on one XCD: 96%8==0), qt = id/96.
// 4 waves, 16 q-rows each. K/V staged via global_load_lds, XOR-swizzled via
// pre-swizzled global source addresses, double-buffered, 1 barrier/tile,
// prefetch-before-compute.
__global__ __launch_bounds__(256) void k_attn(const unsigned short* __restrict__ Qw,
                                              const unsigned short* __restrict__ Kw,
                                              const unsigned short* __restrict__ Vt,
                                              unsigned short* __restrict__ Ctx,
                                              float* __restrict__ mv) {
  const int id = blockIdx.x;
  const int bh = id % 96;
  const int q0 = (id / 96) * 64;
  const int tid = threadIdx.x, w = tid >> 6, l = tid & 63, lr = l & 15, lg = l >> 4;
  const unsigned short* Qp = Qw + (size_t)bh * 512 * 64;
  const unsigned short* Kp = Kw + (size_t)bh * 1024 * 64;
  const unsigned short* Vp = Vt + (size_t)bh * 64 * 1024;

  __shared__ __align__(16) unsigned short Ks[2][4096];  // [64 kv][64 d] swizzled
  __shared__ __align__(16) unsigned short Vs[2][4096];  // [64 d][64 kv] swizzled
  __shared__ __align__(16) unsigned short P[4 * 16 * 72];  // [wave][q=16][kv=64 pad 72]

  const int j1 = 2 * w, j2 = 2 * w + 1;
  const int rA = j1 * 8 + (l >> 3), cA = (l & 7) ^ (rA & 7);
  const int rB = j2 * 8 + (l >> 3), cB = (l & 7) ^ (rB & 7);
  const unsigned short* kSrcA = Kp + rA * 64 + cA * 8;   // + kv0*64 per tile
  const unsigned short* kSrcB = Kp + rB * 64 + cB * 8;
  const unsigned short* vSrcA = Vp + rA * 1024 + cA * 8; // + kv0 per tile
  const unsigned short* vSrcB = Vp + rB * 1024 + cB * 8;

  const int s0 = lr * 64 + ((lg ^ (lr & 7)) * 8);
  const int s1 = lr * 64 + (((lg + 4) ^ (lr & 7)) * 8);

  unsigned short* prow = P + (w * 16 + lr) * 72;
  const unsigned short* prd = prow + lg * 8;
  const int qrow = q0 + w * 16 + lr;
  const bf16x8 qf0 = *(const bf16x8*)(Qp + (size_t)qrow * 64 + lg * 8);
  const bf16x8 qf1 = *(const bf16x8*)(Qp + (size_t)qrow * 64 + 32 + lg * 8);

  f32x4 accc[4] = {};
  float vs0 = 0.f, vs1 = 0.f, vs2 = 0.f, vs3 = 0.f;  // V column-sum partials (qt==0)
  float z = 0.f;

  glds16(kSrcA, &Ks[0][j1 * 512]);
  glds16(kSrcB, &Ks[0][j2 * 512]);
  glds16(vSrcA, &Vs[0][j1 * 512]);
  glds16(vSrcB, &Vs[0][j2 * 512]);
  __syncthreads();

  for (int t = 0; t < 16; ++t) {
    const int pcur = t & 1;
    if (t < 15) {
      const int kv0 = (t + 1) * 64;
      glds16(kSrcA + (size_t)kv0 * 64, &Ks[1 - pcur][j1 * 512]);
      glds16(kSrcB + (size_t)kv0 * 64, &Ks[1 - pcur][j2 * 512]);
      glds16(vSrcA + kv0, &Vs[1 - pcur][j1 * 512]);
      glds16(vSrcB + kv0, &Vs[1 - pcur][j2 * 512]);
    }
    const unsigned short* Kb = Ks[pcur];
    const unsigned short* Vb = Vs[pcur];
    f32x4 ss[4] = {};
#pragma unroll
    for (int m = 0; m < 4; ++m) {
      bf16x8 k0 = *(const bf16x8*)(Kb + m * 1024 + s0);
      bf16x8 k1 = *(const bf16x8*)(Kb + m * 1024 + s1);
      ss[m] = mfma16(k0, qf0, ss[m]);
      ss[m] = mfma16(k1, qf1, ss[m]);
    }
#pragma unroll
    for (int m = 0; m < 4; ++m) {
      float p0 = exp2f(ss[m][0]), p1 = exp2f(ss[m][1]);
      float p2 = exp2f(ss[m][2]), p3 = exp2f(ss[m][3]);
      z += (p0 + p1) + (p2 + p3);
      uint2 pw;
      pw.x = packbf(p0, p1); pw.y = packbf(p2, p3);
      *(uint2*)(prow + m * 16 + lg * 4) = pw;
    }
    bf16x8 pb0 = *(const bf16x8*)prd;
    bf16x8 pb1 = *(const bf16x8*)(prd + 32);
#pragma unroll
    for (int m = 0; m < 4; ++m) {
      bf16x8 v0 = *(const bf16x8*)(Vb + m * 1024 + s0);
      bf16x8 v1 = *(const bf16x8*)(Vb + m * 1024 + s1);
      if (id < 96) {  // V column sums: each wave covers every (dh,kv) exactly once
        float sv = 0.f;
#pragma unroll
        for (int jj = 0; jj < 8; ++jj) sv += (float)v0[jj] + (float)v1[jj];
        if (m == 0) vs0 += sv; else if (m == 1) vs1 += sv;
        else if (m == 2) vs2 += sv; else vs3 += sv;
      }
      accc[m] = mfma16(v0, pb0, accc[m]);
      accc[m] = mfma16(v1, pb1, accc[m]);
    }
    __syncthreads();
  }

  const int b = bh / 12, h = bh - b * 12;
  if (id < 96) {
    vs0 += __shfl_xor(vs0, 16, 64); vs0 += __shfl_xor(vs0, 32, 64);
    vs1 += __shfl_xor(vs1, 16, 64); vs1 += __shfl_xor(vs1, 32, 64);
    vs2 += __shfl_xor(vs2, 16, 64); vs2 += __shfl_xor(vs2, 32, 64);
    vs3 += __shfl_xor(vs3, 16, 64); vs3 += __shfl_xor(vs3, 32, 64);
    if (w == 0 && lg == 0) {
      float* mp = mv + b * 768 + h * 64 + lr;
      mp[0] = vs0 * (1.f / 1024.f);
      mp[16] = vs1 * (1.f / 1024.f);
      mp[32] = vs2 * (1.f / 1024.f);
      mp[48] = vs3 * (1.f / 1024.f);
    }
  }

  z += __shfl_xor(z, 16, 64);
  z += __shfl_xor(z, 32, 64);
  const float zinv = 1.0f / z;
  unsigned short* crow = Ctx + ((size_t)b * 512 + qrow) * 768 + h * 64 + lg * 4;
#pragma unroll
  for (int m = 0; m < 4; ++m) {
    uint2 pv;
    pv.x = packbf(accc[m][0] * zinv, accc[m][1] * zinv);
    pv.y = packbf(accc[m][2] * zinv, accc[m][3] * zinv);
    *(uint2*)(crow + m * 16) = pv;
  }
}

// ---------------- O-proj GEMM (blocks 0..191) + tail broadcast (blocks 192..239) -----
// GEMM: M=4096 (s<512 rows), N=768, K=768, BK=32 double-buffered.
// Tail: orow[b] = mv[b]@Wo + bo -> out rows s>=512 (uniform-softmax rows).
__global__ __launch_bounds__(256) void k_gemm_o(const unsigned short* __restrict__ Ctx,
                                                const unsigned short* __restrict__ WtO,
                                                const float* __restrict__ mv,
                                                const float* __restrict__ Wo,
                                                const float* __restrict__ bo,
                                                float* __restrict__ out) {
  __shared__ __align__(16) unsigned short As0[4096], Bs0[4096], As1[4096], Bs1[4096];
  __shared__ float mvs[768];
  __shared__ float cvals[128];
  const int tid = threadIdx.x;
  if (blockIdx.x >= 192) {  // ---- tail ----
    const int tb = blockIdx.x - 192;
    const int b = tb / 6, n0 = (tb - b * 6) * 128;
    for (int i = tid; i < 768; i += 256) mvs[i] = mv[b * 768 + i];
    __syncthreads();
    const int col = n0 + (tid >> 1);
    const int half = tid & 1;
    float a = 0.f;
    const int kend = half * 384 + 384;
    for (int k = half * 384; k < kend; ++k)
      a += mvs[k] * Wo[(size_t)k * 768 + col];
    a += __shfl_xor(a, 1, 64);
    if (half == 0) cvals[col - n0] = a + bo[col];
    __syncthreads();
    const float4 c4 = ((const float4*)cvals)[tid & 31];
    const int srow = tid >> 5;  // 0..7
    float* obase = out + ((size_t)b * 1024 + 512 + srow) * 768 + n0;
    for (int r = 0; r < 512; r += 8)
      ((float4*)(obase + (size_t)r * 768))[tid & 31] = c4;
    return;
  }
  const int m0 = (blockIdx.x / 6) * 128, n0 = (blockIdx.x % 6) * 128;
  const int w = tid >> 6, l = tid & 63, lr = l & 15, lg = l >> 4;
  const int wm = w >> 1, wn = w & 1;
  const unsigned short* gA = Ctx + (size_t)(m0 + (tid >> 2)) * 768 + (tid & 3) * 8;
  const unsigned short* gB = WtO + (size_t)(n0 + (tid >> 2)) * 768 + (tid & 3) * 8;
  const int woff = w * 512;
  const int rAo = (wm * 64 + lr) * 32 + lg * 8;
  const int rBo = (wn * 64 + lr) * 32 + lg * 8;
  f32x4 acc[4][4] = {};

#define O_STAGE(bufA, bufB, ko)                                                \
  {                                                                            \
    glds16(gA + (ko), bufA + woff);                                            \
    glds16(gA + 64 * 768 + (ko), bufA + woff + 2048);                          \
    glds16(gB + (ko), bufB + woff);                                            \
    glds16(gB + 64 * 768 + (ko), bufB + woff + 2048);                          \
  }
#define O_COMPUTE(bufA, bufB)                                                  \
  {                                                                            \
    bf16x8 af[4], bfr[4];                                                      \
    _Pragma("unroll") for (int i = 0; i < 4; ++i)                              \
      af[i] = *(const bf16x8*)(bufA + rAo + i * 512);                          \
    _Pragma("unroll") for (int i = 0; i < 4; ++i)                              \
      bfr[i] = *(const bf16x8*)(bufB + rBo + i * 512);                         \
    _Pragma("unroll") for (int i = 0; i < 4; ++i)                              \
      _Pragma("unroll") for (int j = 0; j < 4; ++j)                            \
        acc[i][j] = mfma16(af[i], bfr[j], acc[i][j]);                          \
  }

  O_STAGE(As0, Bs0, 0);
  __syncthreads();
  for (int kk = 0; kk < 12; ++kk) {
    const int ko = kk * 64;
    O_STAGE(As1, Bs1, ko + 32);
    O_COMPUTE(As0, Bs0);
    __syncthreads();
    if (kk < 11) { O_STAGE(As0, Bs0, ko + 64); }
    O_COMPUTE(As1, Bs1);
    __syncthreads();
  }
#undef O_STAGE
#undef O_COMPUTE

  const int rbase = m0 + wm * 64 + lg * 4;
  const int cbase = n0 + wn * 64 + lr;
#pragma unroll
  for (int nf = 0; nf < 4; ++nf) {
    const int n = cbase + nf * 16;
    const float bias = bo[n];
#pragma unroll
    for (int mf = 0; mf < 4; ++mf) {
      const int r = rbase + mf * 16;
      const int b = r >> 9, s = r & 511;
      float* op = out + ((size_t)b * 1024 + s) * 768 + n;
#pragma unroll
      for (int rg = 0; rg < 4; ++rg) op[(size_t)rg * 768] = acc[mf][nf][rg] + bias;
    }
  }
}

extern "C" void kernel_launch(void* const* d_in, const int* in_sizes, int n_in,
                              void* d_out, int out_size, void* d_ws, size_t ws_size,
                              hipStream_t stream) {
  const float* X  = (const float*)d_in[0];
  const float* Wq = (const float*)d_in[1];
  const float* bq = (const float*)d_in[2];
  const float* Wk = (const float*)d_in[3];
  const float* bk = (const float*)d_in[4];
  const float* Wv = (const float*)d_in[5];
  const float* bv = (const float*)d_in[6];
  const float* Wo = (const float*)d_in[7];
  const float* bo = (const float*)d_in[8];
  float* out = (float*)d_out;
  char* ws = (char*)d_ws;

  unsigned short* Xbf = (unsigned short*)(ws);                // 8192x768 bf16   12,582,912
  unsigned short* Wt  = (unsigned short*)(ws + 12582912);     // 3072x768 bf16    4,718,592
  unsigned short* Qw  = (unsigned short*)(ws + 17301504);     // 96x512x64 bf16   6,291,456
  unsigned short* Kw  = (unsigned short*)(ws + 23592960);     // 96x1024x64      12,582,912
  unsigned short* Vt  = (unsigned short*)(ws + 36175872);     // 96x64x1024      12,582,912
  unsigned short* Ctx = (unsigned short*)(ws + 48758784);     // 4096x768 bf16    6,291,456
  float* mv   = (float*)(ws + 55050240);                      // 8x768 f32

  k_prep<<<3648, 256, 0, stream>>>(X, Wq, Wk, Wv, Wo, Xbf, Wt);
  k_gemm_qkv<<<960, 128, 0, stream>>>(Xbf, Wt, bq, bk, bv, Qw, Kw, Vt);
  k_attn<<<768, 256, 0, stream>>>(Qw, Kw, Vt, Ctx, mv);
  k_gemm_o<<<240, 256, 0, stream>>>(Ctx, Wt + (size_t)2304 * 768, mv, Wo, bo, out);
}

// Round 9
// 199.677 us; speedup vs baseline: 1.0672x; 1.0672x over previous
//
#include <hip/hip_runtime.h>
#include <hip/hip_bf16.h>
#include <cstdint>

// B=8, S=1024, D=768, H=12, DH=64. PATCHES/2 = 512.
// Pipeline (4 dispatches):
//  k_prep    : X fp32 -> bf16  AND  Wq/Wk/Wv/Wo fp32 [K][N] -> bf16 [N][K] (stacked)
//  k_gemm_qkv: X@W{q,k,v}+b (BK=64, 4 waves, single-buffer -- empirically best: 47.7us)
//              -> Qw[bh][512][64] (pre-scaled log2e/8), Kw[bh][1024][64], Vt[bh][64][1024]
//  k_attn    : rows<512: ctx = softmax(QK^T)V -> Ctx bf16 [4096][768]; qt==0 blocks
//              also accumulate mv[b][768] = mean_s V. setprio around MFMA clusters (T5).
//  k_gemm_o  : out rows s<512 = Ctx@Wo + bo (dbuf); blocks >=192 do the tail
//              (orow[b]=mv[b]@Wo+bo broadcast into out rows s>=512)

typedef __bf16 bf16_t;
typedef bf16_t bf16x8 __attribute__((ext_vector_type(8)));
typedef float f32x4 __attribute__((ext_vector_type(4)));

#define QSCALE 0.18033688011112042f  // log2(e)/8

__device__ __forceinline__ f32x4 mfma16(bf16x8 a, bf16x8 b, f32x4 c) {
  return __builtin_amdgcn_mfma_f32_16x16x32_bf16(a, b, c, 0, 0, 0);
}
__device__ __forceinline__ unsigned packbf(float x, float y) {
  union { bf16_t h; unsigned short u; } a, b;
  a.h = (bf16_t)x; b.h = (bf16_t)y;
  return (unsigned)a.u | ((unsigned)b.u << 16);
}
__device__ __forceinline__ unsigned short tobf(float x) {
  union { bf16_t h; unsigned short u; } a; a.h = (bf16_t)x; return a.u;
}
__device__ __forceinline__ void glds16(const void* g, void* s) {
  __builtin_amdgcn_global_load_lds((const __attribute__((address_space(1))) void*)g,
                                   (__attribute__((address_space(3))) void*)s, 16, 0, 0);
}

// ---------------- prep: X->bf16 (blocks 0..3071) + W transpose (blocks 3072..3647) ----
__global__ __launch_bounds__(256) void k_prep(const float* __restrict__ X,
                                              const float* __restrict__ Wq,
                                              const float* __restrict__ Wk,
                                              const float* __restrict__ Wv,
                                              const float* __restrict__ Wo,
                                              unsigned short* __restrict__ Xbf,
                                              unsigned short* __restrict__ Wt) {
  __shared__ float tile[64][65];
  if (blockIdx.x < 3072) {
    int i = blockIdx.x * 256 + threadIdx.x;  // 786432 groups of 8 floats
    const float4* p = (const float4*)X;
    float4 a = p[2 * i], b = p[2 * i + 1];
    uint4 o;
    o.x = packbf(a.x, a.y); o.y = packbf(a.z, a.w);
    o.z = packbf(b.x, b.y); o.w = packbf(b.z, b.w);
    ((uint4*)Xbf)[i] = o;
    return;
  }
  int id = blockIdx.x - 3072;       // 576 transpose blocks
  int which = id / 144;
  int rem = id - which * 144;
  const float* W = (which == 0) ? Wq : (which == 1) ? Wk : (which == 2) ? Wv : Wo;
  int k0 = (rem / 12) * 64, n0 = (rem % 12) * 64;
  int t = threadIdx.x;
  int c = t & 63, r0 = t >> 6;
#pragma unroll
  for (int i = 0; i < 16; ++i) {
    int r = r0 + i * 4;
    tile[r][c] = W[(size_t)(k0 + r) * 768 + n0 + c];
  }
  __syncthreads();
#pragma unroll
  for (int i = 0; i < 16; ++i) {
    int nr = r0 + i * 4;
    Wt[(size_t)(which * 768 + n0 + nr) * 768 + k0 + c] = tobf(tile[c][nr]);
  }
}

// ---------------- QKV GEMM: M=8192 (Q tiles skipped for s>=512), N=2304, K=768 ----------
// BK=64: LDS [kh][128 rows][32 cols] per operand (16 KB each), 12 k-iters,
// 32 MFMA per iter, 2 barriers per iter. (R5 kernel -- measured 47.7 us.)
__global__ __launch_bounds__(256) void k_gemm_qkv(
    const unsigned short* __restrict__ Xbf, const unsigned short* __restrict__ Wt,
    const float* __restrict__ bq, const float* __restrict__ bk, const float* __restrict__ bv,
    unsigned short* __restrict__ Qw, unsigned short* __restrict__ Kw,
    unsigned short* __restrict__ Vt) {
  __shared__ __align__(16) unsigned short As[8192], Bs[8192];
  int id = blockIdx.x;
  int mt, nt;
  if (id < 576) { int mf = id / 18; mt = ((mf >> 2) << 3) + (mf & 3); nt = id - mf * 18; }
  else { int j = id - 576; int mh = j / 12; mt = ((mh >> 2) << 3) + 4 + (mh & 3); nt = 6 + (j - mh * 12); }
  const int m0 = mt * 128, n0 = nt * 128;
  const int tid = threadIdx.x, w = tid >> 6, l = tid & 63, lr = l & 15, lg = l >> 4;
  const int wm = w >> 1, wn = w & 1;
  // staging: chunk c (1KB) = [kh=c>>3][rows (c&7)*16 .. +15][32 cols]; lane: row +=
  // l>>2, col = (l&3)*8. Wave w stages chunks {w, w+4, w+8, w+12}.
  const unsigned short* gA = Xbf + (size_t)(m0 + (l >> 2)) * 768 + (l & 3) * 8;
  const unsigned short* gB = Wt + (size_t)(n0 + (l >> 2)) * 768 + (l & 3) * 8;
  const size_t rlo = (size_t)(w * 16) * 768, rhi = (size_t)((4 + w) * 16) * 768;
  unsigned short* sA0 = As + w * 512;
  unsigned short* sB0 = Bs + w * 512;
  // fragment read base: row = wm*64 + i*16 + lr, col = lg*8 (within kh-half)
  const unsigned short* rA = As + (wm * 64 + lr) * 32 + lg * 8;
  const unsigned short* rB = Bs + (wn * 64 + lr) * 32 + lg * 8;
  f32x4 acc[4][4] = {};
  for (int kt = 0; kt < 12; ++kt) {
    const int ko = kt * 64;
    glds16(gA + rlo + ko, sA0);            glds16(gA + rhi + ko, sA0 + 2048);
    glds16(gA + rlo + ko + 32, sA0 + 4096); glds16(gA + rhi + ko + 32, sA0 + 6144);
    glds16(gB + rlo + ko, sB0);            glds16(gB + rhi + ko, sB0 + 2048);
    glds16(gB + rlo + ko + 32, sB0 + 4096); glds16(gB + rhi + ko + 32, sB0 + 6144);
    __syncthreads();
#pragma unroll
    for (int kh = 0; kh < 2; ++kh) {
      bf16x8 af[4], bfr[4];
#pragma unroll
      for (int i = 0; i < 4; ++i) af[i] = *(const bf16x8*)(rA + kh * 4096 + i * 512);
#pragma unroll
      for (int i = 0; i < 4; ++i) bfr[i] = *(const bf16x8*)(rB + kh * 4096 + i * 512);
#pragma unroll
      for (int i = 0; i < 4; ++i)
#pragma unroll
        for (int j = 0; j < 4; ++j) acc[i][j] = mfma16(af[i], bfr[j], acc[i][j]);
    }
    __syncthreads();
  }
  // epilogue: C row = m0+wm*64+mf*16+lg*4+reg ; col = n0+wn*64+nf*16+lr
  const int rbase = m0 + wm * 64 + lg * 4;
  const int cbase = n0 + wn * 64 + lr;
#pragma unroll
  for (int nf = 0; nf < 4; ++nf) {
    const int n = cbase + nf * 16;
#pragma unroll
    for (int mf = 0; mf < 4; ++mf) {
      const int r = rbase + mf * 16;
      const int b = r >> 10, s = r & 1023;
      if (n < 768) {  // Q (only s<512 tiles reach here by construction)
        const int h = n >> 6, dh = n & 63;
        const float bias = bq[n];
        unsigned short* qp = Qw + ((size_t)(b * 12 + h) * 512 + s) * 64 + dh;
#pragma unroll
        for (int rg = 0; rg < 4; ++rg)
          qp[(size_t)rg * 64] = tobf((acc[mf][nf][rg] + bias) * QSCALE);
      } else if (n < 1536) {  // K
        const int d = n - 768, h = d >> 6, dh = d & 63;
        const float bias = bk[d];
        unsigned short* kp = Kw + ((size_t)(b * 12 + h) * 1024 + s) * 64 + dh;
#pragma unroll
        for (int rg = 0; rg < 4; ++rg)
          kp[(size_t)rg * 64] = tobf(acc[mf][nf][rg] + bias);
      } else {  // V -> transposed Vt[bh][dh][s], 4 consecutive s packed as 8B
        const int d = n - 1536, h = d >> 6, dh = d & 63;
        const float bias = bv[d];
        uint2 pv;
        pv.x = packbf(acc[mf][nf][0] + bias, acc[mf][nf][1] + bias);
        pv.y = packbf(acc[mf][nf][2] + bias, acc[mf][nf][3] + bias);
        *(uint2*)(Vt + ((size_t)(b * 12 + h) * 64 + dh) * 1024 + s) = pv;
      }
    }
  }
}

// ---------------- attention for q rows < 512 (+ mean-of-V for qt==0 blocks) ----------
// 1D grid 768: bh = id%96 (all 8 q-tiles of a bh on one XCD: 96%8==0), qt = id/96.
// 4 waves, 16 q-rows each. K/V staged via global_load_lds, XOR-swizzled via
// pre-swizzled global source addresses, double-buffered, 1 barrier/tile,
// prefetch-before-compute. T5: setprio(1) around MFMA clusters.
__global__ __launch_bounds__(256) void k_attn(const unsigned short* __restrict__ Qw,
                                              const unsigned short* __restrict__ Kw,
                                              const unsigned short* __restrict__ Vt,
                                              unsigned short* __restrict__ Ctx,
                                              float* __restrict__ mv) {
  const int id = blockIdx.x;
  const int bh = id % 96;
  const int q0 = (id / 96) * 64;
  const int tid = threadIdx.x, w = tid >> 6, l = tid & 63, lr = l & 15, lg = l >> 4;
  const unsigned short* Qp = Qw + (size_t)bh * 512 * 64;
  const unsigned short* Kp = Kw + (size_t)bh * 1024 * 64;
  const unsigned short* Vp = Vt + (size_t)bh * 64 * 1024;

  __shared__ __align__(16) unsigned short Ks[2][4096];  // [64 kv][64 d] swizzled
  __shared__ __align__(16) unsigned short Vs[2][4096];  // [64 d][64 kv] swizzled
  __shared__ __align__(16) unsigned short P[4 * 16 * 72];  // [wave][q=16][kv=64 pad 72]

  const int j1 = 2 * w, j2 = 2 * w + 1;
  const int rA = j1 * 8 + (l >> 3), cA = (l & 7) ^ (rA & 7);
  const int rB = j2 * 8 + (l >> 3), cB = (l & 7) ^ (rB & 7);
  const unsigned short* kSrcA = Kp + rA * 64 + cA * 8;   // + kv0*64 per tile
  const unsigned short* kSrcB = Kp + rB * 64 + cB * 8;
  const unsigned short* vSrcA = Vp + rA * 1024 + cA * 8; // + kv0 per tile
  const unsigned short* vSrcB = Vp + rB * 1024 + cB * 8;

  const int s0 = lr * 64 + ((lg ^ (lr & 7)) * 8);
  const int s1 = lr * 64 + (((lg + 4) ^ (lr & 7)) * 8);

  unsigned short* prow = P + (w * 16 + lr) * 72;
  const unsigned short* prd = prow + lg * 8;
  const int qrow = q0 + w * 16 + lr;
  const bf16x8 qf0 = *(const bf16x8*)(Qp + (size_t)qrow * 64 + lg * 8);
  const bf16x8 qf1 = *(const bf16x8*)(Qp + (size_t)qrow * 64 + 32 + lg * 8);

  f32x4 accc[4] = {};
  float vs0 = 0.f, vs1 = 0.f, vs2 = 0.f, vs3 = 0.f;  // V column-sum partials (qt==0)
  float z = 0.f;

  glds16(kSrcA, &Ks[0][j1 * 512]);
  glds16(kSrcB, &Ks[0][j2 * 512]);
  glds16(vSrcA, &Vs[0][j1 * 512]);
  glds16(vSrcB, &Vs[0][j2 * 512]);
  __syncthreads();

  for (int t = 0; t < 16; ++t) {
    const int pcur = t & 1;
    if (t < 15) {
      const int kv0 = (t + 1) * 64;
      glds16(kSrcA + (size_t)kv0 * 64, &Ks[1 - pcur][j1 * 512]);
      glds16(kSrcB + (size_t)kv0 * 64, &Ks[1 - pcur][j2 * 512]);
      glds16(vSrcA + kv0, &Vs[1 - pcur][j1 * 512]);
      glds16(vSrcB + kv0, &Vs[1 - pcur][j2 * 512]);
    }
    const unsigned short* Kb = Ks[pcur];
    const unsigned short* Vb = Vs[pcur];
    f32x4 ss[4] = {};
    __builtin_amdgcn_s_setprio(1);
#pragma unroll
    for (int m = 0; m < 4; ++m) {
      bf16x8 k0 = *(const bf16x8*)(Kb + m * 1024 + s0);
      bf16x8 k1 = *(const bf16x8*)(Kb + m * 1024 + s1);
      ss[m] = mfma16(k0, qf0, ss[m]);
      ss[m] = mfma16(k1, qf1, ss[m]);
    }
    __builtin_amdgcn_s_setprio(0);
#pragma unroll
    for (int m = 0; m < 4; ++m) {
      float p0 = exp2f(ss[m][0]), p1 = exp2f(ss[m][1]);
      float p2 = exp2f(ss[m][2]), p3 = exp2f(ss[m][3]);
      z += (p0 + p1) + (p2 + p3);
      uint2 pw;
      pw.x = packbf(p0, p1); pw.y = packbf(p2, p3);
      *(uint2*)(prow + m * 16 + lg * 4) = pw;
    }
    bf16x8 pb0 = *(const bf16x8*)prd;
    bf16x8 pb1 = *(const bf16x8*)(prd + 32);
    __builtin_amdgcn_s_setprio(1);
#pragma unroll
    for (int m = 0; m < 4; ++m) {
      bf16x8 v0 = *(const bf16x8*)(Vb + m * 1024 + s0);
      bf16x8 v1 = *(const bf16x8*)(Vb + m * 1024 + s1);
      if (id < 96) {  // V column sums: each wave covers every (dh,kv) exactly once
        float sv = 0.f;
#pragma unroll
        for (int jj = 0; jj < 8; ++jj) sv += (float)v0[jj] + (float)v1[jj];
        if (m == 0) vs0 += sv; else if (m == 1) vs1 += sv;
        else if (m == 2) vs2 += sv; else vs3 += sv;
      }
      accc[m] = mfma16(v0, pb0, accc[m]);
      accc[m] = mfma16(v1, pb1, accc[m]);
    }
    __builtin_amdgcn_s_setprio(0);
    __syncthreads();
  }

  const int b = bh / 12, h = bh - b * 12;
  if (id < 96) {
    vs0 += __shfl_xor(vs0, 16, 64); vs0 += __shfl_xor(vs0, 32, 64);
    vs1 += __shfl_xor(vs1, 16, 64); vs1 += __shfl_xor(vs1, 32, 64);
    vs2 += __shfl_xor(vs2, 16, 64); vs2 += __shfl_xor(vs2, 32, 64);
    vs3 += __shfl_xor(vs3, 16, 64); vs3 += __shfl_xor(vs3, 32, 64);
    if (w == 0 && lg == 0) {
      float* mp = mv + b * 768 + h * 64 + lr;
      mp[0] = vs0 * (1.f / 1024.f);
      mp[16] = vs1 * (1.f / 1024.f);
      mp[32] = vs2 * (1.f / 1024.f);
      mp[48] = vs3 * (1.f / 1024.f);
    }
  }

  z += __shfl_xor(z, 16, 64);
  z += __shfl_xor(z, 32, 64);
  const float zinv = 1.0f / z;
  unsigned short* crow = Ctx + ((size_t)b * 512 + qrow) * 768 + h * 64 + lg * 4;
#pragma unroll
  for (int m = 0; m < 4; ++m) {
    uint2 pv;
    pv.x = packbf(accc[m][0] * zinv, accc[m][1] * zinv);
    pv.y = packbf(accc[m][2] * zinv, accc[m][3] * zinv);
    *(uint2*)(crow + m * 16) = pv;
  }
}

// ---------------- O-proj GEMM (blocks 0..191) + tail broadcast (blocks 192..239) -----
// GEMM: M=4096 (s<512 rows), N=768, K=768, BK=32 double-buffered.
// Tail: orow[b] = mv[b]@Wo + bo -> out rows s>=512 (uniform-softmax rows).
__global__ __launch_bounds__(256) void k_gemm_o(const unsigned short* __restrict__ Ctx,
                                                const unsigned short* __restrict__ WtO,
                                                const float* __restrict__ mv,
                                                const float* __restrict__ Wo,
                                                const float* __restrict__ bo,
                                                float* __restrict__ out) {
  __shared__ __align__(16) unsigned short As0[4096], Bs0[4096], As1[4096], Bs1[4096];
  __shared__ float mvs[768];
  __shared__ float cvals[128];
  const int tid = threadIdx.x;
  if (blockIdx.x >= 192) {  // ---- tail ----
    const int tb = blockIdx.x - 192;
    const int b = tb / 6, n0 = (tb - b * 6) * 128;
    for (int i = tid; i < 768; i += 256) mvs[i] = mv[b * 768 + i];
    __syncthreads();
    const int col = n0 + (tid >> 1);
    const int half = tid & 1;
    float a = 0.f;
    const int kend = half * 384 + 384;
    for (int k = half * 384; k < kend; ++k)
      a += mvs[k] * Wo[(size_t)k * 768 + col];
    a += __shfl_xor(a, 1, 64);
    if (half == 0) cvals[col - n0] = a + bo[col];
    __syncthreads();
    const float4 c4 = ((const float4*)cvals)[tid & 31];
    const int srow = tid >> 5;  // 0..7
    float* obase = out + ((size_t)b * 1024 + 512 + srow) * 768 + n0;
    for (int r = 0; r < 512; r += 8)
      ((float4*)(obase + (size_t)r * 768))[tid & 31] = c4;
    return;
  }
  const int m0 = (blockIdx.x / 6) * 128, n0 = (blockIdx.x % 6) * 128;
  const int w = tid >> 6, l = tid & 63, lr = l & 15, lg = l >> 4;
  const int wm = w >> 1, wn = w & 1;
  const unsigned short* gA = Ctx + (size_t)(m0 + (tid >> 2)) * 768 + (tid & 3) * 8;
  const unsigned short* gB = WtO + (size_t)(n0 + (tid >> 2)) * 768 + (tid & 3) * 8;
  const int woff = w * 512;
  const int rAo = (wm * 64 + lr) * 32 + lg * 8;
  const int rBo = (wn * 64 + lr) * 32 + lg * 8;
  f32x4 acc[4][4] = {};

#define O_STAGE(bufA, bufB, ko)                                                \
  {                                                                            \
    glds16(gA + (ko), bufA + woff);                                            \
    glds16(gA + 64 * 768 + (ko), bufA + woff + 2048);                          \
    glds16(gB + (ko), bufB + woff);                                            \
    glds16(gB + 64 * 768 + (ko), bufB + woff + 2048);                          \
  }
#define O_COMPUTE(bufA, bufB)                                                  \
  {                                                                            \
    bf16x8 af[4], bfr[4];                                                      \
    _Pragma("unroll") for (int i = 0; i < 4; ++i)                              \
      af[i] = *(const bf16x8*)(bufA + rAo + i * 512);                          \
    _Pragma("unroll") for (int i = 0; i < 4; ++i)                              \
      bfr[i] = *(const bf16x8*)(bufB + rBo + i * 512);                         \
    _Pragma("unroll") for (int i = 0; i < 4; ++i)                              \
      _Pragma("unroll") for (int j = 0; j < 4; ++j)                            \
        acc[i][j] = mfma16(af[i], bfr[j], acc[i][j]);                          \
  }

  O_STAGE(As0, Bs0, 0);
  __syncthreads();
  for (int kk = 0; kk < 12; ++kk) {
    const int ko = kk * 64;
    O_STAGE(As1, Bs1, ko + 32);
    O_COMPUTE(As0, Bs0);
    __syncthreads();
    if (kk < 11) { O_STAGE(As0, Bs0, ko + 64); }
    O_COMPUTE(As1, Bs1);
    __syncthreads();
  }
#undef O_STAGE
#undef O_COMPUTE

  const int rbase = m0 + wm * 64 + lg * 4;
  const int cbase = n0 + wn * 64 + lr;
#pragma unroll
  for (int nf = 0; nf < 4; ++nf) {
    const int n = cbase + nf * 16;
    const float bias = bo[n];
#pragma unroll
    for (int mf = 0; mf < 4; ++mf) {
      const int r = rbase + mf * 16;
      const int b = r >> 9, s = r & 511;
      float* op = out + ((size_t)b * 1024 + s) * 768 + n;
#pragma unroll
      for (int rg = 0; rg < 4; ++rg) op[(size_t)rg * 768] = acc[mf][nf][rg] + bias;
    }
  }
}

extern "C" void kernel_launch(void* const* d_in, const int* in_sizes, int n_in,
                              void* d_out, int out_size, void* d_ws, size_t ws_size,
                              hipStream_t stream) {
  const float* X  = (const float*)d_in[0];
  const float* Wq = (const float*)d_in[1];
  const float* bq = (const float*)d_in[2];
  const float* Wk = (const float*)d_in[3];
  const float* bk = (const float*)d_in[4];
  const float* Wv = (const float*)d_in[5];
  const float* bv = (const float*)d_in[6];
  const float* Wo = (const float*)d_in[7];
  const float* bo = (const float*)d_in[8];
  float* out = (float*)d_out;
  char* ws = (char*)d_ws;

  unsigned short* Xbf = (unsigned short*)(ws);                // 8192x768 bf16   12,582,912
  unsigned short* Wt  = (unsigned short*)(ws + 12582912);     // 3072x768 bf16    4,718,592
  unsigned short* Qw  = (unsigned short*)(ws + 17301504);     // 96x512x64 bf16   6,291,456
  unsigned short* Kw  = (unsigned short*)(ws + 23592960);     // 96x1024x64      12,582,912
  unsigned short* Vt  = (unsigned short*)(ws + 36175872);     // 96x64x1024      12,582,912
  unsigned short* Ctx = (unsigned short*)(ws + 48758784);     // 4096x768 bf16    6,291,456
  float* mv   = (float*)(ws + 55050240);                      // 8x768 f32

  k_prep<<<3648, 256, 0, stream>>>(X, Wq, Wk, Wv, Wo, Xbf, Wt);
  k_gemm_qkv<<<960, 256, 0, stream>>>(Xbf, Wt, bq, bk, bv, Qw, Kw, Vt);
  k_attn<<<768, 256, 0, stream>>>(Qw, Kw, Vt, Ctx, mv);
  k_gemm_o<<<240, 256, 0, stream>>>(Ctx, Wt + (size_t)2304 * 768, mv, Wo, bo, out);
}

// Round 10
// 198.585 us; speedup vs baseline: 1.0730x; 1.0055x over previous
//
#include <hip/hip_runtime.h>
#include <hip/hip_bf16.h>
#include <cstdint>

// B=8, S=1024, D=768, H=12, DH=64. PATCHES/2 = 512.
// Pipeline (4 dispatches):
//  k_prep    : X fp32 -> bf16  AND  Wq/Wk/Wv/Wo fp32 [K][N] -> bf16 [N][K] (stacked)
//  k_gemm_qkv: X@W{q,k,v}+b (BK=64, 4 waves, single-buffer; bijective XCD swizzle so
//              each XCD's resident blocks share a ~4.9MB L2 working set)
//              -> Qw[bh][512][64] (pre-scaled log2e/8), Kw[bh][1024][64], Vt[bh][64][1024]
//  k_attn    : rows<512: ctx = softmax(QK^T)V -> Ctx bf16 [4096][768]; qt==0 blocks
//              also accumulate mv[b][768] = mean_s V. setprio around MFMA clusters (T5).
//  k_gemm_o  : out rows s<512 = Ctx@Wo + bo (dbuf, XCD-swizzled); blocks >=192 do the
//              tail (orow[b]=mv[b]@Wo+bo broadcast into out rows s>=512)

typedef __bf16 bf16_t;
typedef bf16_t bf16x8 __attribute__((ext_vector_type(8)));
typedef float f32x4 __attribute__((ext_vector_type(4)));

#define QSCALE 0.18033688011112042f  // log2(e)/8

__device__ __forceinline__ f32x4 mfma16(bf16x8 a, bf16x8 b, f32x4 c) {
  return __builtin_amdgcn_mfma_f32_16x16x32_bf16(a, b, c, 0, 0, 0);
}
__device__ __forceinline__ unsigned packbf(float x, float y) {
  union { bf16_t h; unsigned short u; } a, b;
  a.h = (bf16_t)x; b.h = (bf16_t)y;
  return (unsigned)a.u | ((unsigned)b.u << 16);
}
__device__ __forceinline__ unsigned short tobf(float x) {
  union { bf16_t h; unsigned short u; } a; a.h = (bf16_t)x; return a.u;
}
__device__ __forceinline__ void glds16(const void* g, void* s) {
  __builtin_amdgcn_global_load_lds((const __attribute__((address_space(1))) void*)g,
                                   (__attribute__((address_space(3))) void*)s, 16, 0, 0);
}

// ---------------- prep: X->bf16 (blocks 0..3071) + W transpose (blocks 3072..3647) ----
__global__ __launch_bounds__(256) void k_prep(const float* __restrict__ X,
                                              const float* __restrict__ Wq,
                                              const float* __restrict__ Wk,
                                              const float* __restrict__ Wv,
                                              const float* __restrict__ Wo,
                                              unsigned short* __restrict__ Xbf,
                                              unsigned short* __restrict__ Wt) {
  __shared__ float tile[64][65];
  if (blockIdx.x < 3072) {
    int i = blockIdx.x * 256 + threadIdx.x;  // 786432 groups of 8 floats
    const float4* p = (const float4*)X;
    float4 a = p[2 * i], b = p[2 * i + 1];
    uint4 o;
    o.x = packbf(a.x, a.y); o.y = packbf(a.z, a.w);
    o.z = packbf(b.x, b.y); o.w = packbf(b.z, b.w);
    ((uint4*)Xbf)[i] = o;
    return;
  }
  int id = blockIdx.x - 3072;       // 576 transpose blocks
  int which = id / 144;
  int rem = id - which * 144;
  const float* W = (which == 0) ? Wq : (which == 1) ? Wk : (which == 2) ? Wv : Wo;
  int k0 = (rem / 12) * 64, n0 = (rem % 12) * 64;
  int t = threadIdx.x;
  int c = t & 63, r0 = t >> 6;
#pragma unroll
  for (int i = 0; i < 16; ++i) {
    int r = r0 + i * 4;
    tile[r][c] = W[(size_t)(k0 + r) * 768 + n0 + c];
  }
  __syncthreads();
#pragma unroll
  for (int i = 0; i < 16; ++i) {
    int nr = r0 + i * 4;
    Wt[(size_t)(which * 768 + n0 + nr) * 768 + k0 + c] = tobf(tile[c][nr]);
  }
}

// ---------------- QKV GEMM: M=8192 (Q tiles skipped for s>=512), N=2304, K=768 ----------
// BK=64: LDS [kh][128 rows][32 cols] per operand (16 KB each), 12 k-iters,
// 32 MFMA per iter, 2 barriers per iter. Bijective XCD swizzle (960%8==0):
// XCD x gets logical ids [x*120, x*120+120) = 7 A-panels + all B ~ 4.9MB L2 set.
__global__ __launch_bounds__(256) void k_gemm_qkv(
    const unsigned short* __restrict__ Xbf, const unsigned short* __restrict__ Wt,
    const float* __restrict__ bq, const float* __restrict__ bk, const float* __restrict__ bv,
    unsigned short* __restrict__ Qw, unsigned short* __restrict__ Kw,
    unsigned short* __restrict__ Vt) {
  __shared__ __align__(16) unsigned short As[8192], Bs[8192];
  const int hw = blockIdx.x;
  int id = (hw & 7) * 120 + (hw >> 3);  // bijective XCD remap
  int mt, nt;
  if (id < 576) { int mf = id / 18; mt = ((mf >> 2) << 3) + (mf & 3); nt = id - mf * 18; }
  else { int j = id - 576; int mh = j / 12; mt = ((mh >> 2) << 3) + 4 + (mh & 3); nt = 6 + (j - mh * 12); }
  const int m0 = mt * 128, n0 = nt * 128;
  const int tid = threadIdx.x, w = tid >> 6, l = tid & 63, lr = l & 15, lg = l >> 4;
  const int wm = w >> 1, wn = w & 1;
  // staging: chunk c (1KB) = [kh=c>>3][rows (c&7)*16 .. +15][32 cols]; lane: row +=
  // l>>2, col = (l&3)*8. Wave w stages chunks {w, w+4, w+8, w+12}.
  const unsigned short* gA = Xbf + (size_t)(m0 + (l >> 2)) * 768 + (l & 3) * 8;
  const unsigned short* gB = Wt + (size_t)(n0 + (l >> 2)) * 768 + (l & 3) * 8;
  const size_t rlo = (size_t)(w * 16) * 768, rhi = (size_t)((4 + w) * 16) * 768;
  unsigned short* sA0 = As + w * 512;
  unsigned short* sB0 = Bs + w * 512;
  // fragment read base: row = wm*64 + i*16 + lr, col = lg*8 (within kh-half)
  const unsigned short* rA = As + (wm * 64 + lr) * 32 + lg * 8;
  const unsigned short* rB = Bs + (wn * 64 + lr) * 32 + lg * 8;
  f32x4 acc[4][4] = {};
  for (int kt = 0; kt < 12; ++kt) {
    const int ko = kt * 64;
    glds16(gA + rlo + ko, sA0);            glds16(gA + rhi + ko, sA0 + 2048);
    glds16(gA + rlo + ko + 32, sA0 + 4096); glds16(gA + rhi + ko + 32, sA0 + 6144);
    glds16(gB + rlo + ko, sB0);            glds16(gB + rhi + ko, sB0 + 2048);
    glds16(gB + rlo + ko + 32, sB0 + 4096); glds16(gB + rhi + ko + 32, sB0 + 6144);
    __syncthreads();
#pragma unroll
    for (int kh = 0; kh < 2; ++kh) {
      bf16x8 af[4], bfr[4];
#pragma unroll
      for (int i = 0; i < 4; ++i) af[i] = *(const bf16x8*)(rA + kh * 4096 + i * 512);
#pragma unroll
      for (int i = 0; i < 4; ++i) bfr[i] = *(const bf16x8*)(rB + kh * 4096 + i * 512);
#pragma unroll
      for (int i = 0; i < 4; ++i)
#pragma unroll
        for (int j = 0; j < 4; ++j) acc[i][j] = mfma16(af[i], bfr[j], acc[i][j]);
    }
    __syncthreads();
  }
  // epilogue: C row = m0+wm*64+mf*16+lg*4+reg ; col = n0+wn*64+nf*16+lr
  const int rbase = m0 + wm * 64 + lg * 4;
  const int cbase = n0 + wn * 64 + lr;
#pragma unroll
  for (int nf = 0; nf < 4; ++nf) {
    const int n = cbase + nf * 16;
#pragma unroll
    for (int mf = 0; mf < 4; ++mf) {
      const int r = rbase + mf * 16;
      const int b = r >> 10, s = r & 1023;
      if (n < 768) {  // Q (only s<512 tiles reach here by construction)
        const int h = n >> 6, dh = n & 63;
        const float bias = bq[n];
        unsigned short* qp = Qw + ((size_t)(b * 12 + h) * 512 + s) * 64 + dh;
#pragma unroll
        for (int rg = 0; rg < 4; ++rg)
          qp[(size_t)rg * 64] = tobf((acc[mf][nf][rg] + bias) * QSCALE);
      } else if (n < 1536) {  // K
        const int d = n - 768, h = d >> 6, dh = d & 63;
        const float bias = bk[d];
        unsigned short* kp = Kw + ((size_t)(b * 12 + h) * 1024 + s) * 64 + dh;
#pragma unroll
        for (int rg = 0; rg < 4; ++rg)
          kp[(size_t)rg * 64] = tobf(acc[mf][nf][rg] + bias);
      } else {  // V -> transposed Vt[bh][dh][s], 4 consecutive s packed as 8B
        const int d = n - 1536, h = d >> 6, dh = d & 63;
        const float bias = bv[d];
        uint2 pv;
        pv.x = packbf(acc[mf][nf][0] + bias, acc[mf][nf][1] + bias);
        pv.y = packbf(acc[mf][nf][2] + bias, acc[mf][nf][3] + bias);
        *(uint2*)(Vt + ((size_t)(b * 12 + h) * 64 + dh) * 1024 + s) = pv;
      }
    }
  }
}

// ---------------- attention for q rows < 512 (+ mean-of-V for qt==0 blocks) ----------
// 1D grid 768: bh = id%96 (all 8 q-tiles of a bh on one XCD: 96%8==0), qt = id/96.
// 4 waves, 16 q-rows each. K/V staged via global_load_lds, XOR-swizzled via
// pre-swizzled global source addresses, double-buffered, 1 barrier/tile,
// prefetch-before-compute. T5: setprio(1) around MFMA clusters.
__global__ __launch_bounds__(256) void k_attn(const unsigned short* __restrict__ Qw,
                                              const unsigned short* __restrict__ Kw,
                                              const unsigned short* __restrict__ Vt,
                                              unsigned short* __restrict__ Ctx,
                                              float* __restrict__ mv) {
  const int id = blockIdx.x;
  const int bh = id % 96;
  const int q0 = (id / 96) * 64;
  const int tid = threadIdx.x, w = tid >> 6, l = tid & 63, lr = l & 15, lg = l >> 4;
  const unsigned short* Qp = Qw + (size_t)bh * 512 * 64;
  const unsigned short* Kp = Kw + (size_t)bh * 1024 * 64;
  const unsigned short* Vp = Vt + (size_t)bh * 64 * 1024;

  __shared__ __align__(16) unsigned short Ks[2][4096];  // [64 kv][64 d] swizzled
  __shared__ __align__(16) unsigned short Vs[2][4096];  // [64 d][64 kv] swizzled
  __shared__ __align__(16) unsigned short P[4 * 16 * 72];  // [wave][q=16][kv=64 pad 72]

  const int j1 = 2 * w, j2 = 2 * w + 1;
  const int rA = j1 * 8 + (l >> 3), cA = (l & 7) ^ (rA & 7);
  const int rB = j2 * 8 + (l >> 3), cB = (l & 7) ^ (rB & 7);
  const unsigned short* kSrcA = Kp + rA * 64 + cA * 8;   // + kv0*64 per tile
  const unsigned short* kSrcB = Kp + rB * 64 + cB * 8;
  const unsigned short* vSrcA = Vp + rA * 1024 + cA * 8; // + kv0 per tile
  const unsigned short* vSrcB = Vp + rB * 1024 + cB * 8;

  const int s0 = lr * 64 + ((lg ^ (lr & 7)) * 8);
  const int s1 = lr * 64 + (((lg + 4) ^ (lr & 7)) * 8);

  unsigned short* prow = P + (w * 16 + lr) * 72;
  const unsigned short* prd = prow + lg * 8;
  const int qrow = q0 + w * 16 + lr;
  const bf16x8 qf0 = *(const bf16x8*)(Qp + (size_t)qrow * 64 + lg * 8);
  const bf16x8 qf1 = *(const bf16x8*)(Qp + (size_t)qrow * 64 + 32 + lg * 8);

  f32x4 accc[4] = {};
  float vs0 = 0.f, vs1 = 0.f, vs2 = 0.f, vs3 = 0.f;  // V column-sum partials (qt==0)
  float z = 0.f;

  glds16(kSrcA, &Ks[0][j1 * 512]);
  glds16(kSrcB, &Ks[0][j2 * 512]);
  glds16(vSrcA, &Vs[0][j1 * 512]);
  glds16(vSrcB, &Vs[0][j2 * 512]);
  __syncthreads();

  for (int t = 0; t < 16; ++t) {
    const int pcur = t & 1;
    if (t < 15) {
      const int kv0 = (t + 1) * 64;
      glds16(kSrcA + (size_t)kv0 * 64, &Ks[1 - pcur][j1 * 512]);
      glds16(kSrcB + (size_t)kv0 * 64, &Ks[1 - pcur][j2 * 512]);
      glds16(vSrcA + kv0, &Vs[1 - pcur][j1 * 512]);
      glds16(vSrcB + kv0, &Vs[1 - pcur][j2 * 512]);
    }
    const unsigned short* Kb = Ks[pcur];
    const unsigned short* Vb = Vs[pcur];
    f32x4 ss[4] = {};
    __builtin_amdgcn_s_setprio(1);
#pragma unroll
    for (int m = 0; m < 4; ++m) {
      bf16x8 k0 = *(const bf16x8*)(Kb + m * 1024 + s0);
      bf16x8 k1 = *(const bf16x8*)(Kb + m * 1024 + s1);
      ss[m] = mfma16(k0, qf0, ss[m]);
      ss[m] = mfma16(k1, qf1, ss[m]);
    }
    __builtin_amdgcn_s_setprio(0);
#pragma unroll
    for (int m = 0; m < 4; ++m) {
      float p0 = exp2f(ss[m][0]), p1 = exp2f(ss[m][1]);
      float p2 = exp2f(ss[m][2]), p3 = exp2f(ss[m][3]);
      z += (p0 + p1) + (p2 + p3);
      uint2 pw;
      pw.x = packbf(p0, p1); pw.y = packbf(p2, p3);
      *(uint2*)(prow + m * 16 + lg * 4) = pw;
    }
    bf16x8 pb0 = *(const bf16x8*)prd;
    bf16x8 pb1 = *(const bf16x8*)(prd + 32);
    __builtin_amdgcn_s_setprio(1);
#pragma unroll
    for (int m = 0; m < 4; ++m) {
      bf16x8 v0 = *(const bf16x8*)(Vb + m * 1024 + s0);
      bf16x8 v1 = *(const bf16x8*)(Vb + m * 1024 + s1);
      if (id < 96) {  // V column sums: each wave covers every (dh,kv) exactly once
        float sv = 0.f;
#pragma unroll
        for (int jj = 0; jj < 8; ++jj) sv += (float)v0[jj] + (float)v1[jj];
        if (m == 0) vs0 += sv; else if (m == 1) vs1 += sv;
        else if (m == 2) vs2 += sv; else vs3 += sv;
      }
      accc[m] = mfma16(v0, pb0, accc[m]);
      accc[m] = mfma16(v1, pb1, accc[m]);
    }
    __builtin_amdgcn_s_setprio(0);
    __syncthreads();
  }

  const int b = bh / 12, h = bh - b * 12;
  if (id < 96) {
    vs0 += __shfl_xor(vs0, 16, 64); vs0 += __shfl_xor(vs0, 32, 64);
    vs1 += __shfl_xor(vs1, 16, 64); vs1 += __shfl_xor(vs1, 32, 64);
    vs2 += __shfl_xor(vs2, 16, 64); vs2 += __shfl_xor(vs2, 32, 64);
    vs3 += __shfl_xor(vs3, 16, 64); vs3 += __shfl_xor(vs3, 32, 64);
    if (w == 0 && lg == 0) {
      float* mp = mv + b * 768 + h * 64 + lr;
      mp[0] = vs0 * (1.f / 1024.f);
      mp[16] = vs1 * (1.f / 1024.f);
      mp[32] = vs2 * (1.f / 1024.f);
      mp[48] = vs3 * (1.f / 1024.f);
    }
  }

  z += __shfl_xor(z, 16, 64);
  z += __shfl_xor(z, 32, 64);
  const float zinv = 1.0f / z;
  unsigned short* crow = Ctx + ((size_t)b * 512 + qrow) * 768 + h * 64 + lg * 4;
#pragma unroll
  for (int m = 0; m < 4; ++m) {
    uint2 pv;
    pv.x = packbf(accc[m][0] * zinv, accc[m][1] * zinv);
    pv.y = packbf(accc[m][2] * zinv, accc[m][3] * zinv);
    *(uint2*)(crow + m * 16) = pv;
  }
}

// ---------------- O-proj GEMM (logical 0..191) + tail broadcast (logical 192..239) ---
// GEMM: M=4096 (s<512 rows), N=768, K=768, BK=32 double-buffered. XCD swizzle
// (240%8==0, q=30). Tail: orow[b] = mv[b]@Wo + bo -> out rows s>=512.
__global__ __launch_bounds__(256) void k_gemm_o(const unsigned short* __restrict__ Ctx,
                                                const unsigned short* __restrict__ WtO,
                                                const float* __restrict__ mv,
                                                const float* __restrict__ Wo,
                                                const float* __restrict__ bo,
                                                float* __restrict__ out) {
  __shared__ __align__(16) unsigned short As0[4096], Bs0[4096], As1[4096], Bs1[4096];
  __shared__ float mvs[768];
  __shared__ float cvals[128];
  const int tid = threadIdx.x;
  const int hw = blockIdx.x;
  const int lid = (hw & 7) * 30 + (hw >> 3);  // bijective XCD remap
  if (lid >= 192) {  // ---- tail ----
    const int tb = lid - 192;
    const int b = tb / 6, n0 = (tb - b * 6) * 128;
    for (int i = tid; i < 768; i += 256) mvs[i] = mv[b * 768 + i];
    __syncthreads();
    const int col = n0 + (tid >> 1);
    const int half = tid & 1;
    float a = 0.f;
    const int kend = half * 384 + 384;
    for (int k = half * 384; k < kend; ++k)
      a += mvs[k] * Wo[(size_t)k * 768 + col];
    a += __shfl_xor(a, 1, 64);
    if (half == 0) cvals[col - n0] = a + bo[col];
    __syncthreads();
    const float4 c4 = ((const float4*)cvals)[tid & 31];
    const int srow = tid >> 5;  // 0..7
    float* obase = out + ((size_t)b * 1024 + 512 + srow) * 768 + n0;
    for (int r = 0; r < 512; r += 8)
      ((float4*)(obase + (size_t)r * 768))[tid & 31] = c4;
    return;
  }
  const int m0 = (lid / 6) * 128, n0 = (lid % 6) * 128;
  const int w = tid >> 6, l = tid & 63, lr = l & 15, lg = l >> 4;
  const int wm = w >> 1, wn = w & 1;
  const unsigned short* gA = Ctx + (size_t)(m0 + (tid >> 2)) * 768 + (tid & 3) * 8;
  const unsigned short* gB = WtO + (size_t)(n0 + (tid >> 2)) * 768 + (tid & 3) * 8;
  const int woff = w * 512;
  const int rAo = (wm * 64 + lr) * 32 + lg * 8;
  const int rBo = (wn * 64 + lr) * 32 + lg * 8;
  f32x4 acc[4][4] = {};

#define O_STAGE(bufA, bufB, ko)                                                \
  {                                                                            \
    glds16(gA + (ko), bufA + woff);                                            \
    glds16(gA + 64 * 768 + (ko), bufA + woff + 2048);                          \
    glds16(gB + (ko), bufB + woff);                                            \
    glds16(gB + 64 * 768 + (ko), bufB + woff + 2048);                          \
  }
#define O_COMPUTE(bufA, bufB)                                                  \
  {                                                                            \
    bf16x8 af[4], bfr[4];                                                      \
    _Pragma("unroll") for (int i = 0; i < 4; ++i)                              \
      af[i] = *(const bf16x8*)(bufA + rAo + i * 512);                          \
    _Pragma("unroll") for (int i = 0; i < 4; ++i)                              \
      bfr[i] = *(const bf16x8*)(bufB + rBo + i * 512);                         \
    _Pragma("unroll") for (int i = 0; i < 4; ++i)                              \
      _Pragma("unroll") for (int j = 0; j < 4; ++j)                            \
        acc[i][j] = mfma16(af[i], bfr[j], acc[i][j]);                          \
  }

  O_STAGE(As0, Bs0, 0);
  __syncthreads();
  for (int kk = 0; kk < 12; ++kk) {
    const int ko = kk * 64;
    O_STAGE(As1, Bs1, ko + 32);
    O_COMPUTE(As0, Bs0);
    __syncthreads();
    if (kk < 11) { O_STAGE(As0, Bs0, ko + 64); }
    O_COMPUTE(As1, Bs1);
    __syncthreads();
  }
#undef O_STAGE
#undef O_COMPUTE

  const int rbase = m0 + wm * 64 + lg * 4;
  const int cbase = n0 + wn * 64 + lr;
#pragma unroll
  for (int nf = 0; nf < 4; ++nf) {
    const int n = cbase + nf * 16;
    const float bias = bo[n];
#pragma unroll
    for (int mf = 0; mf < 4; ++mf) {
      const int r = rbase + mf * 16;
      const int b = r >> 9, s = r & 511;
      float* op = out + ((size_t)b * 1024 + s) * 768 + n;
#pragma unroll
      for (int rg = 0; rg < 4; ++rg) op[(size_t)rg * 768] = acc[mf][nf][rg] + bias;
    }
  }
}

extern "C" void kernel_launch(void* const* d_in, const int* in_sizes, int n_in,
                              void* d_out, int out_size, void* d_ws, size_t ws_size,
                              hipStream_t stream) {
  const float* X  = (const float*)d_in[0];
  const float* Wq = (const float*)d_in[1];
  const float* bq = (const float*)d_in[2];
  const float* Wk = (const float*)d_in[3];
  const float* bk = (const float*)d_in[4];
  const float* Wv = (const float*)d_in[5];
  const float* bv = (const float*)d_in[6];
  const float* Wo = (const float*)d_in[7];
  const float* bo = (const float*)d_in[8];
  float* out = (float*)d_out;
  char* ws = (char*)d_ws;

  unsigned short* Xbf = (unsigned short*)(ws);                // 8192x768 bf16   12,582,912
  unsigned short* Wt  = (unsigned short*)(ws + 12582912);     // 3072x768 bf16    4,718,592
  unsigned short* Qw  = (unsigned short*)(ws + 17301504);     // 96x512x64 bf16   6,291,456
  unsigned short* Kw  = (unsigned short*)(ws + 23592960);     // 96x1024x64      12,582,912
  unsigned short* Vt  = (unsigned short*)(ws + 36175872);     // 96x64x1024      12,582,912
  unsigned short* Ctx = (unsigned short*)(ws + 48758784);     // 4096x768 bf16    6,291,456
  float* mv   = (float*)(ws + 55050240);                      // 8x768 f32

  k_prep<<<3648, 256, 0, stream>>>(X, Wq, Wk, Wv, Wo, Xbf, Wt);
  k_gemm_qkv<<<960, 256, 0, stream>>>(Xbf, Wt, bq, bk, bv, Qw, Kw, Vt);
  k_attn<<<768, 256, 0, stream>>>(Qw, Kw, Vt, Ctx, mv);
  k_gemm_o<<<240, 256, 0, stream>>>(Ctx, Wt + (size_t)2304 * 768, mv, Wo, bo, out);
}